// Round 4
// baseline (62.289 us; speedup 1.0000x reference)
//
#include <hip/hip_runtime.h>
#include <hip/hip_bf16.h>
#include <float.h>

#define NGROUPS 128
#define SLOT    512   // per-group LDS capacity; group sizes ~128 +/- 11 (512 = 34 sigma)

// Single fused kernel: one block per group.
// Phase 1: block scans idx (int4 loads), compacts member coords+ids into LDS SoA.
// Phase 2: one wave per member (strided): per-lane sorted top-16 register chain
//          over LDS candidates, then K cooperative DPP pop-merges.
// Deterministic: LDS compaction order is race-dependent, but each member's
// candidate MULTISET is identical, and k-th-smallest is a set function.

#define DPP_MIN_STEP(v, CTRL)                                                  \
    v = fminf(v, __int_as_float(__builtin_amdgcn_update_dpp(                   \
            0x7f7fffff /*FLT_MAX bits*/, __float_as_int(v), CTRL, 0xf, 0xf,    \
            false)))

__global__ __launch_bounds__(1024) void kde_fused(
        const float* __restrict__ x,
        const int* __restrict__ idx,
        const int* __restrict__ Kptr,
        int M,
        float* __restrict__ out) {
    __shared__ float sx[SLOT], sy[SLOT], sz[SLOT];
    __shared__ int   sid[SLOT];
    __shared__ int   lc;

    const int g = blockIdx.x;
    const int t = threadIdx.x;
    if (t == 0) lc = 0;
    __syncthreads();

    // ---- phase 1: compact this group's members into LDS ----
#define KDE_TRY(pid_)                                                          \
    do {                                                                       \
        const int pid = (pid_);                                                \
        int p = atomicAdd(&lc, 1);                                             \
        if (p < SLOT) {                                                        \
            sid[p] = pid;                                                      \
            sx[p] = x[3 * pid + 0];                                            \
            sy[p] = x[3 * pid + 1];                                            \
            sz[p] = x[3 * pid + 2];                                            \
        }                                                                      \
    } while (0)

    const int4* __restrict__ idx4 = (const int4*)idx;
    const int M4 = M >> 2;
    for (int i = t; i < M4; i += 1024) {
        const int4 v = idx4[i];
        const int base = i << 2;
        if (v.x == g) KDE_TRY(base + 0);
        if (v.y == g) KDE_TRY(base + 1);
        if (v.z == g) KDE_TRY(base + 2);
        if (v.w == g) KDE_TRY(base + 3);
    }
    for (int i = (M4 << 2) + t; i < M; i += 1024) {  // tail (M % 4 != 0)
        if (idx[i] == g) KDE_TRY(i);
    }
#undef KDE_TRY
    __syncthreads();

    const int c = (lc < SLOT) ? lc : SLOT;
    const int K = Kptr[0];

    const int wave = t >> 6;
    const int lane = t & 63;

    // ---- phase 2: one wave per member, strided over the 16 waves ----
    for (int mi = wave; mi < c; mi += 16) {
        const float xm = sx[mi];
        const float ym = sy[mi];
        const float zm = sz[mi];

        float s0 = FLT_MAX, s1 = FLT_MAX, s2 = FLT_MAX, s3 = FLT_MAX;
        float s4 = FLT_MAX, s5 = FLT_MAX, s6 = FLT_MAX, s7 = FLT_MAX;
        float s8 = FLT_MAX, s9 = FLT_MAX, s10 = FLT_MAX, s11 = FLT_MAX;
        float s12 = FLT_MAX, s13 = FLT_MAX, s14 = FLT_MAX, s15 = FLT_MAX;

#define KNN_INSERT(dval)                                                      \
        do {                                                                  \
            float v_ = (dval);                                                \
            if (v_ < s15) {                                                   \
                float tt_;                                                    \
                if (v_ < s0)  { tt_ = s0;  s0  = v_; v_ = tt_; }              \
                if (v_ < s1)  { tt_ = s1;  s1  = v_; v_ = tt_; }              \
                if (v_ < s2)  { tt_ = s2;  s2  = v_; v_ = tt_; }              \
                if (v_ < s3)  { tt_ = s3;  s3  = v_; v_ = tt_; }              \
                if (v_ < s4)  { tt_ = s4;  s4  = v_; v_ = tt_; }              \
                if (v_ < s5)  { tt_ = s5;  s5  = v_; v_ = tt_; }              \
                if (v_ < s6)  { tt_ = s6;  s6  = v_; v_ = tt_; }              \
                if (v_ < s7)  { tt_ = s7;  s7  = v_; v_ = tt_; }              \
                if (v_ < s8)  { tt_ = s8;  s8  = v_; v_ = tt_; }              \
                if (v_ < s9)  { tt_ = s9;  s9  = v_; v_ = tt_; }              \
                if (v_ < s10) { tt_ = s10; s10 = v_; v_ = tt_; }              \
                if (v_ < s11) { tt_ = s11; s11 = v_; v_ = tt_; }              \
                if (v_ < s12) { tt_ = s12; s12 = v_; v_ = tt_; }              \
                if (v_ < s13) { tt_ = s13; s13 = v_; v_ = tt_; }              \
                if (v_ < s14) { tt_ = s14; s14 = v_; v_ = tt_; }              \
                s15 = v_;                                                     \
            }                                                                 \
        } while (0)

        for (int j = lane; j < c; j += 64) {
            const float dx = sx[j] - xm;
            const float dy = sy[j] - ym;
            const float dz = sz[j] - zm;
            const float d2 = dx * dx + dy * dy + dz * dz;
            KNN_INSERT(d2);
        }
#undef KNN_INSERT

        // K cooperative pops; `ans` ends as the K-th smallest d^2
        // (multiset includes the self-distance 0, matching the reference).
        float ans = FLT_MAX;
        for (int it = 0; it < K; ++it) {
            float v = s0;
            DPP_MIN_STEP(v, 0x111);  // row_shr:1
            DPP_MIN_STEP(v, 0x112);  // row_shr:2
            DPP_MIN_STEP(v, 0x114);  // row_shr:4
            DPP_MIN_STEP(v, 0x118);  // row_shr:8
            DPP_MIN_STEP(v, 0x142);  // row_bcast:15
            DPP_MIN_STEP(v, 0x143);  // row_bcast:31
            const float m = __int_as_float(
                __builtin_amdgcn_readlane(__float_as_int(v), 63));
            ans = m;
            const unsigned long long bal = __ballot(s0 == m);
            const int leader = (int)__ffsll(bal) - 1;
            if (lane == leader) {  // pop exactly one instance (handles ties)
                s0 = s1; s1 = s2; s2 = s3; s3 = s4; s4 = s5; s5 = s6; s6 = s7;
                s7 = s8; s8 = s9; s9 = s10; s10 = s11; s11 = s12; s12 = s13;
                s13 = s14; s14 = s15; s15 = FLT_MAX;
            }
        }

        if (lane == 0) {
            // dim = NI-1 = 2: volume = pi*r^2 = pi*ans (ans is squared dist).
            float p = (c < K) ? (1.0f / (float)c)
                              : (3.14159265358979323846f * ans / (float)(K - 1));
            out[sid[mi]] = p;
        }
    }
}

extern "C" void kernel_launch(void* const* d_in, const int* in_sizes, int n_in,
                              void* d_out, int out_size, void* d_ws, size_t ws_size,
                              hipStream_t stream) {
    const float* x   = (const float*)d_in[0];
    const int*   idx = (const int*)d_in[1];
    const int*   Kp  = (const int*)d_in[2];
    float* out = (float*)d_out;

    const int M = in_sizes[1];  // 16384

    kde_fused<<<NGROUPS, 1024, 0, stream>>>(x, idx, Kp, M, out);
}

// Round 5
// 31.099 us; speedup vs baseline: 2.0029x; 2.0029x over previous
//
#include <hip/hip_runtime.h>
#include <hip/hip_bf16.h>
#include <float.h>

#define NGROUPS 128
#define SLOT    512   // fixed per-group slot (group sizes ~128±11; 512 is 30+ sigma)

// ws layout: [0,512B) counts (int[128]) | [512B, 512B + 128*512*16B) gx float4 slots
//
// Structure (fastest measured, r2/r3 — both at the ~39us harness-fill floor):
//   kernel A: one block per group, int4-vectorized scan of idx, compact the
//             group's member coords into a fixed global float4 slot.
//   kernel B: one 64-lane wave per point; per-lane sorted top-16 register
//             chain over the group's slot, then K cooperative DPP pop-merges.
// Determinism: slot order is race-dependent, but each point's candidate
// MULTISET is identical every run, and k-th-smallest is a set function.

__global__ __launch_bounds__(512) void kde_bucket(
        const int* __restrict__ idx,
        const float* __restrict__ x,
        int M,
        int* __restrict__ counts,
        float4* __restrict__ gx) {
    __shared__ int lc;
    if (threadIdx.x == 0) lc = 0;
    __syncthreads();
    const int g = blockIdx.x;
    float4* __restrict__ slot = gx + (size_t)g * SLOT;

#define KDE_TRY(pid_)                                                          \
    do {                                                                       \
        const int pid = (pid_);                                                \
        int p = atomicAdd(&lc, 1);                                             \
        if (p < SLOT) {                                                        \
            float4 v;                                                          \
            v.x = x[3 * pid + 0];                                              \
            v.y = x[3 * pid + 1];                                              \
            v.z = x[3 * pid + 2];                                              \
            v.w = 0.0f;                                                        \
            slot[p] = v;                                                       \
        }                                                                      \
    } while (0)

    const int4* __restrict__ idx4 = (const int4*)idx;
    const int M4 = M >> 2;
    for (int i = threadIdx.x; i < M4; i += 512) {
        const int4 v = idx4[i];
        const int base = i << 2;
        if (v.x == g) KDE_TRY(base + 0);
        if (v.y == g) KDE_TRY(base + 1);
        if (v.z == g) KDE_TRY(base + 2);
        if (v.w == g) KDE_TRY(base + 3);
    }
    for (int i = (M4 << 2) + threadIdx.x; i < M; i += 512) {  // tail (M%4)
        if (idx[i] == g) KDE_TRY(i);
    }
#undef KDE_TRY
    __syncthreads();
    if (threadIdx.x == 0) counts[g] = (lc < SLOT) ? lc : SLOT;
}

#define DPP_MIN_STEP(v, CTRL)                                                  \
    v = fminf(v, __int_as_float(__builtin_amdgcn_update_dpp(                   \
            0x7f7fffff /*FLT_MAX bits*/, __float_as_int(v), CTRL, 0xf, 0xf,    \
            false)))

__global__ __launch_bounds__(256) void kde_select(
        const float* __restrict__ x,
        const int* __restrict__ idx,
        const float4* __restrict__ gx,
        const int* __restrict__ counts,
        const int* __restrict__ Kptr,
        int M,
        float* __restrict__ out) {
    const int wid  = (blockIdx.x << 2) | (threadIdx.x >> 6);  // point id
    const int lane = threadIdx.x & 63;
    if (wid >= M) return;

    const int g = idx[wid];
    const int c = counts[g];
    const int K = Kptr[0];
    const float4* __restrict__ slot = gx + (size_t)g * SLOT;

    const float xm = x[3 * wid + 0];
    const float ym = x[3 * wid + 1];
    const float zm = x[3 * wid + 2];

    float s0 = FLT_MAX, s1 = FLT_MAX, s2 = FLT_MAX, s3 = FLT_MAX;
    float s4 = FLT_MAX, s5 = FLT_MAX, s6 = FLT_MAX, s7 = FLT_MAX;
    float s8 = FLT_MAX, s9 = FLT_MAX, s10 = FLT_MAX, s11 = FLT_MAX;
    float s12 = FLT_MAX, s13 = FLT_MAX, s14 = FLT_MAX, s15 = FLT_MAX;

#define KNN_INSERT(dval)                                                      \
    do {                                                                      \
        float v_ = (dval);                                                    \
        if (v_ < s15) {                                                       \
            float tt_;                                                        \
            if (v_ < s0)  { tt_ = s0;  s0  = v_; v_ = tt_; }                  \
            if (v_ < s1)  { tt_ = s1;  s1  = v_; v_ = tt_; }                  \
            if (v_ < s2)  { tt_ = s2;  s2  = v_; v_ = tt_; }                  \
            if (v_ < s3)  { tt_ = s3;  s3  = v_; v_ = tt_; }                  \
            if (v_ < s4)  { tt_ = s4;  s4  = v_; v_ = tt_; }                  \
            if (v_ < s5)  { tt_ = s5;  s5  = v_; v_ = tt_; }                  \
            if (v_ < s6)  { tt_ = s6;  s6  = v_; v_ = tt_; }                  \
            if (v_ < s7)  { tt_ = s7;  s7  = v_; v_ = tt_; }                  \
            if (v_ < s8)  { tt_ = s8;  s8  = v_; v_ = tt_; }                  \
            if (v_ < s9)  { tt_ = s9;  s9  = v_; v_ = tt_; }                  \
            if (v_ < s10) { tt_ = s10; s10 = v_; v_ = tt_; }                  \
            if (v_ < s11) { tt_ = s11; s11 = v_; v_ = tt_; }                  \
            if (v_ < s12) { tt_ = s12; s12 = v_; v_ = tt_; }                  \
            if (v_ < s13) { tt_ = s13; s13 = v_; v_ = tt_; }                  \
            if (v_ < s14) { tt_ = s14; s14 = v_; v_ = tt_; }                  \
            s15 = v_;                                                         \
        }                                                                     \
    } while (0)

    for (int j = lane; j < c; j += 64) {
        const float4 v = slot[j];
        const float dx = v.x - xm;
        const float dy = v.y - ym;
        const float dz = v.z - zm;
        const float d2 = dx * dx + dy * dy + dz * dz;
        KNN_INSERT(d2);
    }
#undef KNN_INSERT

    // K cooperative pops; after the loop `ans` is the K-th smallest d^2
    // (multiset includes the self-distance 0, matching the reference).
    float ans = FLT_MAX;
    for (int it = 0; it < K; ++it) {
        float v = s0;
        DPP_MIN_STEP(v, 0x111);  // row_shr:1
        DPP_MIN_STEP(v, 0x112);  // row_shr:2
        DPP_MIN_STEP(v, 0x114);  // row_shr:4
        DPP_MIN_STEP(v, 0x118);  // row_shr:8
        DPP_MIN_STEP(v, 0x142);  // row_bcast:15
        DPP_MIN_STEP(v, 0x143);  // row_bcast:31
        const float m = __int_as_float(
            __builtin_amdgcn_readlane(__float_as_int(v), 63));
        ans = m;
        const unsigned long long bal = __ballot(s0 == m);
        const int leader = (int)__ffsll(bal) - 1;
        if (lane == leader) {  // pop exactly one instance (handles ties)
            s0 = s1; s1 = s2; s2 = s3; s3 = s4; s4 = s5; s5 = s6; s6 = s7;
            s7 = s8; s8 = s9; s9 = s10; s10 = s11; s11 = s12; s12 = s13;
            s13 = s14; s14 = s15; s15 = FLT_MAX;
        }
    }

    if (lane == 0) {
        // dim = NI-1 = 2: volume = pi*r^2 = pi*ans (ans is squared distance).
        float p = (c < K) ? (1.0f / (float)c)
                          : (3.14159265358979323846f * ans / (float)(K - 1));
        out[wid] = p;
    }
}

extern "C" void kernel_launch(void* const* d_in, const int* in_sizes, int n_in,
                              void* d_out, int out_size, void* d_ws, size_t ws_size,
                              hipStream_t stream) {
    const float* x   = (const float*)d_in[0];
    const int*   idx = (const int*)d_in[1];
    const int*   Kp  = (const int*)d_in[2];
    float* out = (float*)d_out;

    const int M = in_sizes[1];  // 16384

    int*    counts = (int*)d_ws;
    float4* gx     = (float4*)((char*)d_ws + 512);

    kde_bucket<<<NGROUPS, 512, 0, stream>>>(idx, x, M, counts, gx);

    const int blocks = (M + 3) / 4;  // 4 waves (points) per 256-thread block
    kde_select<<<blocks, 256, 0, stream>>>(x, idx, gx, counts, Kp, M, out);
}

// Round 6
// 26.928 us; speedup vs baseline: 2.3131x; 1.1549x over previous
//
#include <hip/hip_runtime.h>
#include <hip/hip_bf16.h>
#include <float.h>

#define NGROUPS 128
#define SLOT    512   // per-group slot cap; group sizes ~128±11 (512 = 34 sigma)

// ws layout: [0,512B) counts (int[128]) | [512B, 512B + 128*512*16B) gx float4 slots
//
// kernel A (bucket): one block per group, int4 scan of idx, compact member
//   coords into the group's float4 slot. ~1-2us (measured inference, r5).
// kernel B (select): one 64-lane wave per point. Each lane loads its
//   NR = ceil(c/64) candidates into registers (branch-free, FLT_MAX pad),
//   sorts them with a static network, then pops distinct minima via DPP
//   reduce + ballot-popcount rank until rank >= K. Exact for any c <= 64*NR
//   (every candidate value lives in some lane's registers). Deterministic:
//   slot order races, but the candidate MULTISET is identical each run and
//   k-th-smallest is a set function.

__global__ __launch_bounds__(512) void kde_bucket(
        const int* __restrict__ idx,
        const float* __restrict__ x,
        int M,
        int* __restrict__ counts,
        float4* __restrict__ gx) {
    __shared__ int lc;
    if (threadIdx.x == 0) lc = 0;
    __syncthreads();
    const int g = blockIdx.x;
    float4* __restrict__ slot = gx + (size_t)g * SLOT;

#define KDE_TRY(pid_)                                                          \
    do {                                                                       \
        const int pid = (pid_);                                                \
        int p = atomicAdd(&lc, 1);                                             \
        if (p < SLOT) {                                                        \
            float4 v;                                                          \
            v.x = x[3 * pid + 0];                                              \
            v.y = x[3 * pid + 1];                                              \
            v.z = x[3 * pid + 2];                                              \
            v.w = 0.0f;                                                        \
            slot[p] = v;                                                       \
        }                                                                      \
    } while (0)

    const int4* __restrict__ idx4 = (const int4*)idx;
    const int M4 = M >> 2;
    for (int i = threadIdx.x; i < M4; i += 512) {
        const int4 v = idx4[i];
        const int base = i << 2;
        if (v.x == g) KDE_TRY(base + 0);
        if (v.y == g) KDE_TRY(base + 1);
        if (v.z == g) KDE_TRY(base + 2);
        if (v.w == g) KDE_TRY(base + 3);
    }
    for (int i = (M4 << 2) + threadIdx.x; i < M; i += 512) {  // tail (M%4)
        if (idx[i] == g) KDE_TRY(i);
    }
#undef KDE_TRY
    __syncthreads();
    if (threadIdx.x == 0) counts[g] = (lc < SLOT) ? lc : SLOT;
}

// proven 64-lane min reduce (r2/r3/r5, absmax 0): min lands in lane 63
#define DPP_MIN_STEP(v, CTRL)                                                  \
    v = fminf(v, __int_as_float(__builtin_amdgcn_update_dpp(                   \
            0x7f7fffff /*FLT_MAX bits*/, __float_as_int(v), CTRL, 0xf, 0xf,    \
            false)))

#define CSWAP(a, b)                                                            \
    do { float lo_ = fminf(r[a], r[b]); float hi_ = fmaxf(r[a], r[b]);         \
         r[a] = lo_; r[b] = hi_; } while (0)

template <int NR>
__device__ __forceinline__ float kth_smallest_d2(
        const float4* __restrict__ slot, int c, int K,
        float xm, float ym, float zm, int lane) {
    float r[NR];
#pragma unroll
    for (int k = 0; k < NR; ++k) {
        const int j = lane + 64 * k;          // < 64*NR <= SLOT: load in-bounds
        const float4 v = slot[j];
        const float dx = v.x - xm;
        const float dy = v.y - ym;
        const float dz = v.z - zm;
        const float d2 = dx * dx + dy * dy + dz * dz;
        r[k] = (j < c) ? d2 : FLT_MAX;        // mask stale/poison slots
    }

    // static sorting network, ascending (all indices compile-time)
    if (NR == 4) {
        CSWAP(0, 1); CSWAP(2, 3);
        CSWAP(0, 2); CSWAP(1, 3);
        CSWAP(1, 2);
    } else {  // NR == 8, Batcher odd-even merge, 19 comparators
        CSWAP(0, 1); CSWAP(2, 3); CSWAP(4, 5); CSWAP(6, 7);
        CSWAP(0, 2); CSWAP(1, 3); CSWAP(4, 6); CSWAP(5, 7);
        CSWAP(1, 2); CSWAP(5, 6);
        CSWAP(0, 4); CSWAP(1, 5); CSWAP(2, 6); CSWAP(3, 7);
        CSWAP(2, 4); CSWAP(3, 5);
        CSWAP(1, 2); CSWAP(3, 4); CSWAP(5, 6);
    }

    // pop distinct minima; rank advances by multiplicity (ballot popcount).
    // Exits with ans = K-th smallest (with multiplicity). cnt is wave-uniform.
    float ans = 0.0f;
    int cnt = 0;
    for (int it = 0; it < K; ++it) {
        float v = r[0];
        DPP_MIN_STEP(v, 0x111);  // row_shr:1
        DPP_MIN_STEP(v, 0x112);  // row_shr:2
        DPP_MIN_STEP(v, 0x114);  // row_shr:4
        DPP_MIN_STEP(v, 0x118);  // row_shr:8
        DPP_MIN_STEP(v, 0x142);  // row_bcast:15
        DPP_MIN_STEP(v, 0x143);  // row_bcast:31
        const float m = __int_as_float(
            __builtin_amdgcn_readlane(__float_as_int(v), 63));
        ans = m;
        const bool cond = (r[0] == m);
        cnt += (int)__popcll(__ballot(cond));
#pragma unroll
        for (int k = 0; k < NR - 1; ++k) r[k] = cond ? r[k + 1] : r[k];
        r[NR - 1] = cond ? FLT_MAX : r[NR - 1];
        if (cnt >= K) break;
    }
    return ans;
}

__global__ __launch_bounds__(256) void kde_select(
        const float* __restrict__ x,
        const int* __restrict__ idx,
        const float4* __restrict__ gx,
        const int* __restrict__ counts,
        const int* __restrict__ Kptr,
        int M,
        float* __restrict__ out) {
    const int wid  = (blockIdx.x << 2) | (threadIdx.x >> 6);  // point id
    const int lane = threadIdx.x & 63;
    if (wid >= M) return;

    const int g = idx[wid];
    const int c = counts[g];
    const int K = Kptr[0];
    const float4* __restrict__ slot = gx + (size_t)g * SLOT;

    const float xm = x[3 * wid + 0];
    const float ym = x[3 * wid + 1];
    const float zm = x[3 * wid + 2];

    float ans;
    if (c <= 256) {   // wave-uniform; always taken for this data (c ~ 128±11)
        ans = kth_smallest_d2<4>(slot, c, K, xm, ym, zm, lane);
    } else {          // exact fallback up to the SLOT cap
        ans = kth_smallest_d2<8>(slot, c, K, xm, ym, zm, lane);
    }

    if (lane == 0) {
        // dim = NI-1 = 2: volume = pi*r^2 = pi*ans (ans is squared distance).
        float p = (c < K) ? (1.0f / (float)c)
                          : (3.14159265358979323846f * ans / (float)(K - 1));
        out[wid] = p;
    }
}

extern "C" void kernel_launch(void* const* d_in, const int* in_sizes, int n_in,
                              void* d_out, int out_size, void* d_ws, size_t ws_size,
                              hipStream_t stream) {
    const float* x   = (const float*)d_in[0];
    const int*   idx = (const int*)d_in[1];
    const int*   Kp  = (const int*)d_in[2];
    float* out = (float*)d_out;

    const int M = in_sizes[1];  // 16384

    int*    counts = (int*)d_ws;
    float4* gx     = (float4*)((char*)d_ws + 512);

    kde_bucket<<<NGROUPS, 512, 0, stream>>>(idx, x, M, counts, gx);

    const int blocks = (M + 3) / 4;  // 4 waves (points) per 256-thread block
    kde_select<<<blocks, 256, 0, stream>>>(x, idx, gx, counts, Kp, M, out);
}